// Round 1
// baseline (768.382 us; speedup 1.0000x reference)
//
#include <hip/hip_runtime.h>
#include <math.h>

#define BATCH 8
#define CIN   128
#define COUT  128
#define HH    64
#define WW    64
#define K2c   9
#define OC    27        // 3*K2
#define KDIM  1152      // CIN*K2

// ---------------- K0: transpose weight [o][kidx] -> Wt[kidx][o] ----------------
__global__ __launch_bounds__(256) void k_transpose_w(const float* __restrict__ w,
                                                     float* __restrict__ wt) {
    int tid = blockIdx.x * 256 + threadIdx.x;
    if (tid < COUT * KDIM) {
        int o    = tid & 127;
        int kidx = tid >> 7;
        wt[tid] = w[o * KDIM + kidx];
    }
}

// ---------------- K1: offset conv (27ch, 3x3, pad1) + bias + sigmoid on mask ----
// thread -> 4 consecutive w outputs of one (b, c, h)
__global__ __launch_bounds__(256) void k_offset_conv(const float* __restrict__ x,
                                                     const float* __restrict__ w_off,
                                                     const float* __restrict__ b_off,
                                                     float* __restrict__ om) {
    int t  = blockIdx.x * 256 + threadIdx.x;   // 864 blocks * 256 = 221184 exactly
    int wg = t & 15;
    int h  = (t >> 4) & 63;
    int rest = t >> 10;
    int c  = rest % 27;      // wave-uniform
    int b  = rest / 27;
    int w0 = wg * 4;

    float acc0 = 0.f, acc1 = 0.f, acc2 = 0.f, acc3 = 0.f;
    const float* wbase = w_off + c * KDIM;

    for (int ci = 0; ci < CIN; ++ci) {
        float wt9[9];
#pragma unroll
        for (int q = 0; q < 9; ++q) wt9[q] = wbase[ci * 9 + q];
        const float* xplane = x + ((size_t)(b * CIN + ci)) * (HH * WW);
#pragma unroll
        for (int kh = 0; kh < 3; ++kh) {
            int y = h - 1 + kh;
            if ((unsigned)y < (unsigned)HH) {
                const float* r = xplane + y * WW;
                float v[6];
                v[0] = (w0 > 0) ? r[w0 - 1] : 0.f;
                float4 mid = *reinterpret_cast<const float4*>(r + w0);
                v[1] = mid.x; v[2] = mid.y; v[3] = mid.z; v[4] = mid.w;
                v[5] = (w0 + 4 < WW) ? r[w0 + 4] : 0.f;
#pragma unroll
                for (int kw = 0; kw < 3; ++kw) {
                    float wv = wt9[kh * 3 + kw];
                    acc0 += v[0 + kw] * wv;
                    acc1 += v[1 + kw] * wv;
                    acc2 += v[2 + kw] * wv;
                    acc3 += v[3 + kw] * wv;
                }
            }
        }
    }
    float bb = b_off[c];
    float o0 = acc0 + bb, o1 = acc1 + bb, o2 = acc2 + bb, o3 = acc3 + bb;
    if (c >= 18) {   // mask channels: apply sigmoid here (wave-uniform branch)
        o0 = 1.f / (1.f + expf(-o0));
        o1 = 1.f / (1.f + expf(-o1));
        o2 = 1.f / (1.f + expf(-o2));
        o3 = 1.f / (1.f + expf(-o3));
    }
    float4 res = make_float4(o0, o1, o2, o3);
    *reinterpret_cast<float4*>(om + ((size_t)(b * OC + c)) * (HH * WW) + h * WW + w0) = res;
}

// ---------------- K2: bilinear sampling + GEMM, 8 pixels per block ----------------
__global__ __launch_bounds__(256) void k_sample_gemm(const float* __restrict__ x,
                                                     const float* __restrict__ om,
                                                     const float* __restrict__ wt,   // [kidx][o]
                                                     const float* __restrict__ bias,
                                                     float* __restrict__ out) {
    __shared__ __align__(16) float cols[KDIM * 8];   // [kidx][p]  36864 B
    __shared__ float wts4[72 * 4];
    __shared__ int   y0s[72];
    __shared__ int   x0s[72];
    __shared__ float part[128 * 8];

    int t   = threadIdx.x;
    int pp0 = blockIdx.x * 8;          // 512 blocks per image -> b uniform per block
    int b   = pp0 >> 12;

    // ---- phase 0: bilinear params for 8 pixels x 9 taps ----
    if (t < 72) {
        int p = t / 9, k = t % 9;
        int pp = pp0 + p;
        int hw = pp & 4095;
        int h = hw >> 6, w = hw & 63;
        const float* ob = om + (size_t)(b * OC) * 4096 + h * WW + w;
        float dy = ob[(size_t)k * 4096];
        float dx = ob[(size_t)(9 + k) * 4096];
        float m  = ob[(size_t)(18 + k) * 4096];     // already sigmoided
        float py = dy + (float)(h - 1 + k / 3);
        float px = dx + (float)(w - 1 + k % 3);
        float y0f = floorf(py), x0f = floorf(px);
        float wy = py - y0f, wx = px - x0f;
        y0s[t] = (int)y0f;
        x0s[t] = (int)x0f;
        wts4[t * 4 + 0] = (1.f - wy) * (1.f - wx) * m;
        wts4[t * 4 + 1] = (1.f - wy) * wx * m;
        wts4[t * 4 + 2] = wy * (1.f - wx) * m;
        wts4[t * 4 + 3] = wy * wx * m;
    }
    __syncthreads();

    // ---- phase 1: gather bilinear samples into cols[kidx][p] ----
    {
        int p  = t & 7;
        int cg = t >> 3;               // 0..31
#pragma unroll
        for (int k = 0; k < 9; ++k) {
            int pi = p * 9 + k;
            int y0 = y0s[pi], x0 = x0s[pi];
            float w00 = wts4[pi * 4 + 0], w01 = wts4[pi * 4 + 1];
            float w10 = wts4[pi * 4 + 2], w11 = wts4[pi * 4 + 3];
            bool yv0 = (unsigned)y0 < (unsigned)HH;
            bool yv1 = (unsigned)(y0 + 1) < (unsigned)HH;
            bool xv0 = (unsigned)x0 < (unsigned)WW;
            bool xv1 = (unsigned)(x0 + 1) < (unsigned)WW;
#pragma unroll
            for (int cc = 0; cc < 4; ++cc) {
                int c = cc * 32 + cg;
                const float* xb = x + ((size_t)(b * CIN + c) << 12);
                float v = 0.f;
                int base0 = y0 * WW + x0;
                if (yv0) {
                    if (xv0) v += w00 * xb[base0];
                    if (xv1) v += w01 * xb[base0 + 1];
                }
                if (yv1) {
                    if (xv0) v += w10 * xb[base0 + WW];
                    if (xv1) v += w11 * xb[base0 + WW + 1];
                }
                cols[(c * 9 + k) * 8 + p] = v;
            }
        }
    }
    __syncthreads();

    // ---- phase 2: out[o, 8 pixels] = sum_k wt[k][o] * cols[k][p], k-split in 2 ----
    int o = t & 127, half = t >> 7;
    float acc[8];
#pragma unroll
    for (int j = 0; j < 8; ++j) acc[j] = 0.f;
    int k0 = half * (KDIM / 2);
    const float* wrow = wt + o;
#pragma unroll 4
    for (int kidx = k0; kidx < k0 + KDIM / 2; ++kidx) {
        float wv = wrow[(size_t)kidx * 128];
        const float4* cp = reinterpret_cast<const float4*>(&cols[kidx * 8]);
        float4 c0 = cp[0], c1 = cp[1];
        acc[0] += wv * c0.x; acc[1] += wv * c0.y;
        acc[2] += wv * c0.z; acc[3] += wv * c0.w;
        acc[4] += wv * c1.x; acc[5] += wv * c1.y;
        acc[6] += wv * c1.z; acc[7] += wv * c1.w;
    }
    if (half) {
#pragma unroll
        for (int j = 0; j < 8; ++j) part[o * 8 + j] = acc[j];
    }
    __syncthreads();
    if (!half) {
        float bb = bias[o];
#pragma unroll
        for (int j = 0; j < 8; ++j) {
            float r = acc[j] + part[o * 8 + j] + bb;
            int pp = pp0 + j;
            int hw = pp & 4095;
            out[((size_t)(b * COUT + o) << 12) + hw] = r;
        }
    }
}

// ---------------- host ----------------
extern "C" void kernel_launch(void* const* d_in, const int* in_sizes, int n_in,
                              void* d_out, int out_size, void* d_ws, size_t ws_size,
                              hipStream_t stream) {
    const float* x      = (const float*)d_in[0];
    const float* w_off  = (const float*)d_in[1];
    const float* b_off  = (const float*)d_in[2];
    const float* weight = (const float*)d_in[3];
    const float* bias   = (const float*)d_in[4];
    float* out = (float*)d_out;

    float* om = (float*)d_ws;                         // 884736 floats
    float* wt = om + (size_t)BATCH * OC * HH * WW;    // 147456 floats

    k_transpose_w<<<(COUT * KDIM + 255) / 256, 256, 0, stream>>>(weight, wt);
    k_offset_conv<<<(BATCH * OC * HH * WW / 4 + 255) / 256, 256, 0, stream>>>(x, w_off, b_off, om);
    k_sample_gemm<<<BATCH * HH * WW / 8, 256, 0, stream>>>(x, om, wt, bias, out);
}

// Round 2
// 344.872 us; speedup vs baseline: 2.2280x; 2.2280x over previous
//
#include <hip/hip_runtime.h>
#include <math.h>

#define BATCH 8
#define CIN   128
#define COUT  128
#define HH    64
#define WW    64
#define OC    27        // 3*K2
#define KDIM  1152      // CIN*9

typedef unsigned short u16;
typedef __attribute__((ext_vector_type(8))) short bf16x8;
typedef __attribute__((ext_vector_type(4))) float f32x4;

__device__ __forceinline__ float b2f(u16 u) {
    return __uint_as_float((unsigned)u << 16);
}
__device__ __forceinline__ u16 f2b(float f) {   // RTNE
    unsigned u = __float_as_uint(f);
    return (u16)((u + 0x7fffu + ((u >> 16) & 1u)) >> 16);
}

// ---------------- K_t: x NCHW f32 -> NHWC bf16 ----------------
__global__ __launch_bounds__(256) void k_transpose_x(const float* __restrict__ x,
                                                     u16* __restrict__ xtb) {
    __shared__ float tile[64][65];
    int bid = blockIdx.x;              // 8 b * 2 cblk * 64 hwblk = 1024
    int b   = bid >> 7;
    int c0  = ((bid >> 6) & 1) << 6;
    int hw0 = (bid & 63) << 6;
    int t   = threadIdx.x;
    int lo  = t & 63;
    int cq  = t >> 6;                  // 0..3
#pragma unroll
    for (int r = 0; r < 16; ++r) {
        int c_l = cq * 16 + r;
        tile[c_l][lo] = x[(((size_t)(b * CIN + c0 + c_l)) << 12) + hw0 + lo];
    }
    __syncthreads();
#pragma unroll
    for (int r = 0; r < 16; ++r) {
        int hw_w = cq * 16 + r;
        xtb[((size_t)(b << 12) + hw0 + hw_w) * 128 + c0 + lo] = f2b(tile[lo][hw_w]);
    }
}

// ---------------- K_w: pack weight into B-fragment order, bf16 ----------------
// wbf[((t9*4+s)*8+ni)*64 + l][j] = bf16( weight[co=ni*16+(l&15)][ci=s*32+(l>>4)*8+j][t9] )
__global__ __launch_bounds__(256) void k_pack_w(const float* __restrict__ weight,
                                                u16* __restrict__ wbf) {
    int tid = blockIdx.x * 256 + threadIdx.x;    // 576 blocks, exact
    int j  = tid & 7;
    int l  = (tid >> 3) & 63;
    int ni = (tid >> 9) & 7;
    int s  = (tid >> 12) & 3;
    int t9 = tid >> 14;
    int co = ni * 16 + (l & 15);
    int ci = s * 32 + ((l >> 4) << 3) + j;
    wbf[tid] = f2b(weight[co * KDIM + ci * 9 + t9]);
}

// ---------------- K1: offset conv (27ch, 3x3, pad1) + bias + sigmoid on mask ----
__global__ __launch_bounds__(256) void k_offset_conv(const float* __restrict__ x,
                                                     const float* __restrict__ w_off,
                                                     const float* __restrict__ b_off,
                                                     float* __restrict__ om) {
    int t  = blockIdx.x * 256 + threadIdx.x;   // 864 blocks
    int wg = t & 15;
    int h  = (t >> 4) & 63;
    int rest = t >> 10;
    int c  = rest % 27;
    int b  = rest / 27;
    int w0 = wg * 4;

    float acc0 = 0.f, acc1 = 0.f, acc2 = 0.f, acc3 = 0.f;
    const float* wbase = w_off + c * KDIM;

    for (int ci = 0; ci < CIN; ++ci) {
        float wt9[9];
#pragma unroll
        for (int q = 0; q < 9; ++q) wt9[q] = wbase[ci * 9 + q];
        const float* xplane = x + ((size_t)(b * CIN + ci)) * (HH * WW);
#pragma unroll
        for (int kh = 0; kh < 3; ++kh) {
            int y = h - 1 + kh;
            if ((unsigned)y < (unsigned)HH) {
                const float* r = xplane + y * WW;
                float v[6];
                v[0] = (w0 > 0) ? r[w0 - 1] : 0.f;
                float4 mid = *reinterpret_cast<const float4*>(r + w0);
                v[1] = mid.x; v[2] = mid.y; v[3] = mid.z; v[4] = mid.w;
                v[5] = (w0 + 4 < WW) ? r[w0 + 4] : 0.f;
#pragma unroll
                for (int kw = 0; kw < 3; ++kw) {
                    float wv = wt9[kh * 3 + kw];
                    acc0 += v[0 + kw] * wv;
                    acc1 += v[1 + kw] * wv;
                    acc2 += v[2 + kw] * wv;
                    acc3 += v[3 + kw] * wv;
                }
            }
        }
    }
    float bb = b_off[c];
    float o0 = acc0 + bb, o1 = acc1 + bb, o2 = acc2 + bb, o3 = acc3 + bb;
    if (c >= 18) {
        o0 = 1.f / (1.f + expf(-o0));
        o1 = 1.f / (1.f + expf(-o1));
        o2 = 1.f / (1.f + expf(-o2));
        o3 = 1.f / (1.f + expf(-o3));
    }
    float4 res = make_float4(o0, o1, o2, o3);
    *reinterpret_cast<float4*>(om + ((size_t)(b * OC + c)) * (HH * WW) + h * WW + w0) = res;
}

// ---------------- K2: bilinear sampling (NHWC bf16) + MFMA GEMM ----------------
// block = 32 pixels (half a row), out tile 32px x 128cout, 4 waves
__global__ __launch_bounds__(256) void k_sample_gemm(const u16* __restrict__ xtb,
                                                     const float* __restrict__ om,
                                                     const u16* __restrict__ wbf,
                                                     const float* __restrict__ bias,
                                                     float* __restrict__ out) {
    __shared__ __align__(16) u16 Abuf[2][4096];      // [buf][32px][128ch] bf16, swizzled
    __shared__ int   y0c[288], y1c[288], x0c[288], x1c[288];
    __shared__ float w4[288][4];

    const int t   = threadIdx.x;
    const int pp0 = blockIdx.x << 5;
    const int b   = blockIdx.x >> 7;
    const int h   = (pp0 >> 6) & 63;
    const int w0  = pp0 & 63;

    // ---- phase 0: bilinear params (clamped corners, masked weights) ----
    for (int i = t; i < 288; i += 256) {
        int p  = i / 9;
        int tt = i - p * 9;
        int w  = w0 + p;
        const float* ob = om + ((size_t)b * OC) * 4096 + (h << 6) + w;
        float dy = ob[(size_t)tt << 12];
        float dx = ob[(size_t)(9 + tt) << 12];
        float m  = ob[(size_t)(18 + tt) << 12];   // sigmoided in K1
        float py = dy + (float)(h - 1 + tt / 3);
        float px = dx + (float)(w - 1 + tt % 3);
        float y0f = floorf(py), x0f = floorf(px);
        float wy = py - y0f, wx = px - x0f;
        int y0 = (int)y0f, x0 = (int)x0f;
        int y1 = y0 + 1,   x1 = x0 + 1;
        float vy0 = ((unsigned)y0 < 64u) ? 1.f : 0.f;
        float vy1 = ((unsigned)y1 < 64u) ? 1.f : 0.f;
        float vx0 = ((unsigned)x0 < 64u) ? 1.f : 0.f;
        float vx1 = ((unsigned)x1 < 64u) ? 1.f : 0.f;
        w4[i][0] = (1.f - wy) * (1.f - wx) * m * vy0 * vx0;
        w4[i][1] = (1.f - wy) * wx         * m * vy0 * vx1;
        w4[i][2] = wy         * (1.f - wx) * m * vy1 * vx0;
        w4[i][3] = wy         * wx         * m * vy1 * vx1;
        y0c[i] = min(max(y0, 0), 63);
        y1c[i] = min(max(y1, 0), 63);
        x0c[i] = min(max(x0, 0), 63);
        x1c[i] = min(max(x1, 0), 63);
    }
    __syncthreads();

    f32x4 acc00 = {0.f, 0.f, 0.f, 0.f};
    f32x4 acc01 = {0.f, 0.f, 0.f, 0.f};
    f32x4 acc10 = {0.f, 0.f, 0.f, 0.f};
    f32x4 acc11 = {0.f, 0.f, 0.f, 0.f};

    const int p  = t >> 3;         // sampling: pixel
    const int cg = t & 7;          // sampling: channel group
    const u16* xb = xtb + ((size_t)b << 19);

    const int l   = t & 63;        // mfma: lane
    const int wv  = t >> 6;        // mfma: wave
    const int row0 = l & 15;
    const int kg   = l >> 4;

    auto sample = [&](int tt, int buf) {
        int pi = p * 9 + tt;
        int o00 = ((y0c[pi] << 6) | x0c[pi]) << 7;
        int o01 = ((y0c[pi] << 6) | x1c[pi]) << 7;
        int o10 = ((y1c[pi] << 6) | x0c[pi]) << 7;
        int o11 = ((y1c[pi] << 6) | x1c[pi]) << 7;
        float W00 = w4[pi][0], W01 = w4[pi][1], W10 = w4[pi][2], W11 = w4[pi][3];
        u16* dst = &Abuf[buf][0];
#pragma unroll
        for (int it = 0; it < 4; ++it) {
            int ch = it * 32 + cg * 4;
            ushort4 v00 = *(const ushort4*)(xb + o00 + ch);
            ushort4 v01 = *(const ushort4*)(xb + o01 + ch);
            ushort4 v10 = *(const ushort4*)(xb + o10 + ch);
            ushort4 v11 = *(const ushort4*)(xb + o11 + ch);
            float r0 = W00 * b2f(v00.x) + W01 * b2f(v01.x) + W10 * b2f(v10.x) + W11 * b2f(v11.x);
            float r1 = W00 * b2f(v00.y) + W01 * b2f(v01.y) + W10 * b2f(v10.y) + W11 * b2f(v11.y);
            float r2 = W00 * b2f(v00.z) + W01 * b2f(v01.z) + W10 * b2f(v10.z) + W11 * b2f(v11.z);
            float r3 = W00 * b2f(v00.w) + W01 * b2f(v01.w) + W10 * b2f(v10.w) + W11 * b2f(v11.w);
            ushort4 rv;
            rv.x = f2b(r0); rv.y = f2b(r1); rv.z = f2b(r2); rv.w = f2b(r3);
            int q = ch >> 3;                                   // 16B chunk idx 0..15
            int byteoff = (p << 8) + (((q ^ (p & 15)) << 4)) + ((cg & 1) << 3);
            *(ushort4*)((char*)dst + byteoff) = rv;
        }
    };

    auto domfma = [&](int t9, int buf) {
        const char* Ab = (const char*)&Abuf[buf][0];
#pragma unroll
        for (int s = 0; s < 4; ++s) {
            int q = s * 4 + kg;
            int sw = (q ^ row0) << 4;
            bf16x8 a0 = *(const bf16x8*)(Ab + (row0 << 8) + sw);
            bf16x8 a1 = *(const bf16x8*)(Ab + ((row0 + 16) << 8) + ((q ^ row0) << 4));
            size_t wo = ((size_t)t9 << 14) + (s << 12) + ((size_t)(wv * 2) << 9) + (l << 3);
            bf16x8 b0 = *(const bf16x8*)(wbf + wo);
            bf16x8 b1 = *(const bf16x8*)(wbf + wo + 512);
            acc00 = __builtin_amdgcn_mfma_f32_16x16x32_bf16(a0, b0, acc00, 0, 0, 0);
            acc10 = __builtin_amdgcn_mfma_f32_16x16x32_bf16(a1, b0, acc10, 0, 0, 0);
            acc01 = __builtin_amdgcn_mfma_f32_16x16x32_bf16(a0, b1, acc01, 0, 0, 0);
            acc11 = __builtin_amdgcn_mfma_f32_16x16x32_bf16(a1, b1, acc11, 0, 0, 0);
        }
    };

    sample(0, 0);
    __syncthreads();
    for (int tt = 0; tt < 9; ++tt) {
        if (tt < 8) sample(tt + 1, (tt + 1) & 1);
        domfma(tt, tt & 1);
        __syncthreads();
    }

    // ---- epilogue: acc -> LDS (swizzled) -> coalesced global ----
    {
        float* outs = (float*)&Abuf[0][0];    // 128co x 32px f32 = 16KB (whole Abuf)
        int colbase = wv * 32 + row0;
        int pxg = kg << 2;
        auto st = [&](int co, int px, f32x4 v) {
            *(f32x4*)((char*)outs + (co << 7) + ((((px >> 2) ^ (co & 7))) << 4)) = v;
        };
        st(colbase,      pxg,      acc00);
        st(colbase,      pxg + 16, acc10);
        st(colbase + 16, pxg,      acc01);
        st(colbase + 16, pxg + 16, acc11);
    }
    __syncthreads();
    {
        const float* outs = (const float*)&Abuf[0][0];
        int co = t >> 1, half = t & 1;
        float bb = bias[co];
        float* og = out + (((size_t)(b * COUT + co)) << 12) + (h << 6) + w0 + half * 16;
#pragma unroll
        for (int j = 0; j < 4; ++j) {
            int px = half * 16 + j * 4;
            f32x4 v = *(const f32x4*)((const char*)outs + (co << 7) + ((((px >> 2) ^ (co & 7))) << 4));
            float4 r = make_float4(v.x + bb, v.y + bb, v.z + bb, v.w + bb);
            *reinterpret_cast<float4*>(og + j * 4) = r;
        }
    }
}

// ---------------- host ----------------
extern "C" void kernel_launch(void* const* d_in, const int* in_sizes, int n_in,
                              void* d_out, int out_size, void* d_ws, size_t ws_size,
                              hipStream_t stream) {
    const float* x      = (const float*)d_in[0];
    const float* w_off  = (const float*)d_in[1];
    const float* b_off  = (const float*)d_in[2];
    const float* weight = (const float*)d_in[3];
    const float* bias   = (const float*)d_in[4];
    float* out = (float*)d_out;

    float* om  = (float*)d_ws;                        // 884736 f32
    u16*   xtb = (u16*)(om + 884736);                 // 4194304 u16 (NHWC bf16)
    u16*   wbf = xtb + 4194304;                       // 147456 u16 (packed B-frags)

    k_transpose_x<<<1024, 256, 0, stream>>>(x, xtb);
    k_pack_w<<<576, 256, 0, stream>>>(weight, wbf);
    k_offset_conv<<<864, 256, 0, stream>>>(x, w_off, b_off, om);
    k_sample_gemm<<<BATCH * HH * WW / 32, 256, 0, stream>>>(xtb, om, wbf, bias, out);
}

// Round 3
// 79.090 us; speedup vs baseline: 9.7153x; 4.3605x over previous
//
#include <hip/hip_runtime.h>
#include <math.h>

#define BATCH 8
#define CIN   128
#define COUT  128
#define HH    64
#define WW    64
#define OC    27        // 3*K2
#define KDIM  1152      // CIN*9

typedef unsigned short u16;
typedef __attribute__((ext_vector_type(8))) short bf16x8;
typedef __attribute__((ext_vector_type(4))) float f32x4;

__device__ __forceinline__ float b2f(u16 u) {
    return __uint_as_float((unsigned)u << 16);
}
__device__ __forceinline__ u16 f2b(float f) {   // RTNE
    unsigned u = __float_as_uint(f);
    return (u16)((u + 0x7fffu + ((u >> 16) & 1u)) >> 16);
}

// ---------------- K_t: x NCHW f32 -> NHWC bf16 (hi) + residual (lo) ----------------
__global__ __launch_bounds__(256) void k_transpose_x(const float* __restrict__ x,
                                                     u16* __restrict__ xtb,
                                                     u16* __restrict__ xlo) {
    __shared__ float tile[64][65];
    int bid = blockIdx.x;              // 8 b * 2 cblk * 64 hwblk = 1024
    int b   = bid >> 7;
    int c0  = ((bid >> 6) & 1) << 6;
    int hw0 = (bid & 63) << 6;
    int t   = threadIdx.x;
    int ln  = t & 63;
    int cq  = t >> 6;                  // 0..3
#pragma unroll
    for (int r = 0; r < 16; ++r) {
        int c_l = cq * 16 + r;
        tile[c_l][ln] = x[(((size_t)(b * CIN + c0 + c_l)) << 12) + hw0 + ln];
    }
    __syncthreads();
#pragma unroll
    for (int r = 0; r < 16; ++r) {
        int hw_w = cq * 16 + r;
        float v = tile[ln][hw_w];
        u16 hi = f2b(v);
        u16 lo = f2b(v - b2f(hi));
        size_t dst = ((size_t)(b << 12) + hw0 + hw_w) * 128 + c0 + ln;
        xtb[dst] = hi;
        xlo[dst] = lo;
    }
}

// ---------------- K_w: pack main weight into B-fragment order, bf16 ----------------
__global__ __launch_bounds__(256) void k_pack_w(const float* __restrict__ weight,
                                                u16* __restrict__ wbf) {
    int tid = blockIdx.x * 256 + threadIdx.x;    // 576 blocks, exact
    int j  = tid & 7;
    int l  = (tid >> 3) & 63;
    int ni = (tid >> 9) & 7;
    int s  = (tid >> 12) & 3;
    int t9 = tid >> 14;
    int co = ni * 16 + (l & 15);
    int ci = s * 32 + ((l >> 4) << 3) + j;
    wbf[tid] = f2b(weight[co * KDIM + ci * 9 + t9]);
}

// ---------------- K_wo: pack offset-conv weight, hi/lo split, co padded 27->32 ----
// layout: [split][t9][sg][ni][l][j], split stride 36864
__global__ __launch_bounds__(256) void k_pack_woff(const float* __restrict__ w_off,
                                                   u16* __restrict__ wop) {
    int tid = blockIdx.x * 256 + threadIdx.x;    // 288 blocks, exact (73728)
    int j   = tid & 7;
    int l   = (tid >> 3) & 63;
    int ni  = (tid >> 9) & 1;
    int sg  = (tid >> 10) & 3;
    int rest = tid >> 12;
    int t9  = rest % 9;
    int split = rest / 9;
    int co = ni * 16 + (l & 15);
    int ci = sg * 32 + ((l >> 4) << 3) + j;
    float val = (co < OC) ? w_off[co * KDIM + ci * 9 + t9] : 0.f;
    u16 hi = f2b(val);
    u16 lo = f2b(val - b2f(hi));
    wop[tid] = split ? lo : hi;
}

// ---------------- K1: offset conv via MFMA (implicit GEMM, hi/lo split) ----------
// block = 32 px (half row) x 32 co, 2 waves (16 px each). 1024 blocks.
__global__ __launch_bounds__(128) void k_off_mfma(const u16* __restrict__ xtb,
                                                  const u16* __restrict__ xlo,
                                                  const u16* __restrict__ wop,
                                                  const float* __restrict__ b_off,
                                                  float* __restrict__ om) {
    __shared__ __align__(16) u16 Xh[3 * 34 * 64];   // 13056 B, per-ci-half window
    __shared__ __align__(16) u16 Xl[3 * 34 * 64];

    const int t     = threadIdx.x;
    const int bid   = blockIdx.x;        // b*128 + h*2 + whalf
    const int b     = bid >> 7;
    const int h     = (bid >> 1) & 63;
    const int whalf = bid & 1;
    const int w0    = whalf << 5;
    const int l     = t & 63;
    const int wv    = t >> 6;            // 0,1
    const int kg    = l >> 4;

    f32x4 acc0 = {0.f, 0.f, 0.f, 0.f};   // co 0..15
    f32x4 acc1 = {0.f, 0.f, 0.f, 0.f};   // co 16..31

    for (int half = 0; half < 2; ++half) {
        __syncthreads();
        // ---- stage 3 rows x 34 px x 64 ci (hi+lo), XOR-swizzled ----
        for (int i = t; i < 3 * 34 * 8; i += 128) {
            int row = i / 272;
            int rem = i - row * 272;
            int p = rem >> 3, q = rem & 7;
            int grow = h - 1 + row;
            int gw   = w0 + p - 1;
            int dst  = ((row * 34 + p) << 7) + ((q ^ (p & 7)) << 4);   // bytes
            bf16x8 vh = {0, 0, 0, 0, 0, 0, 0, 0};
            bf16x8 vl = {0, 0, 0, 0, 0, 0, 0, 0};
            if ((unsigned)grow < 64u && (unsigned)gw < 64u) {
                size_t src = ((((size_t)b << 12) + (grow << 6) + gw) << 7) + half * 64 + q * 8;
                vh = *(const bf16x8*)(xtb + src);
                vl = *(const bf16x8*)(xlo + src);
            }
            *(bf16x8*)((char*)Xh + dst) = vh;
            *(bf16x8*)((char*)Xl + dst) = vl;
        }
        __syncthreads();

        // ---- K-loop: 9 taps x 2 chunks, 6 MFMA each ----
        for (int tap = 0; tap < 9; ++tap) {
            int kh = tap / 3, kw = tap - kh * 3;
            int p = wv * 16 + (l & 15) + kw;           // 0..33
            int rowbase = (kh * 34 + p) << 7;
#pragma unroll
            for (int s = 0; s < 2; ++s) {
                int q = s * 4 + kg;
                int off = rowbase + ((q ^ (p & 7)) << 4);
                bf16x8 ah = *(const bf16x8*)((const char*)Xh + off);
                bf16x8 al = *(const bf16x8*)((const char*)Xl + off);
                int sg = half * 2 + s;
                const u16* B  = wop + (((tap * 4 + sg) * 2) << 9) + (l << 3);
                bf16x8 bh0 = *(const bf16x8*)(B);
                bf16x8 bh1 = *(const bf16x8*)(B + 512);
                bf16x8 bl0 = *(const bf16x8*)(B + 36864);
                bf16x8 bl1 = *(const bf16x8*)(B + 36864 + 512);
                acc0 = __builtin_amdgcn_mfma_f32_16x16x32_bf16(ah, bh0, acc0, 0, 0, 0);
                acc1 = __builtin_amdgcn_mfma_f32_16x16x32_bf16(ah, bh1, acc1, 0, 0, 0);
                acc0 = __builtin_amdgcn_mfma_f32_16x16x32_bf16(al, bh0, acc0, 0, 0, 0);
                acc1 = __builtin_amdgcn_mfma_f32_16x16x32_bf16(al, bh1, acc1, 0, 0, 0);
                acc0 = __builtin_amdgcn_mfma_f32_16x16x32_bf16(ah, bl0, acc0, 0, 0, 0);
                acc1 = __builtin_amdgcn_mfma_f32_16x16x32_bf16(ah, bl1, acc1, 0, 0, 0);
            }
        }
    }

    // ---- epilogue: bias (+sigmoid on mask channels), float4 stores ----
    int wpx = w0 + wv * 16 + (kg << 2);
    int co0 = l & 15;            // 0..15: offset channels, no sigmoid
    {
        float bb = b_off[co0];
        float4 r = make_float4(acc0.x + bb, acc0.y + bb, acc0.z + bb, acc0.w + bb);
        *(float4*)(om + (((size_t)(b * OC + co0)) << 12) + (h << 6) + wpx) = r;
    }
    int co1 = co0 + 16;
    if (co1 < OC) {
        float bb = b_off[co1];
        float4 r = make_float4(acc1.x + bb, acc1.y + bb, acc1.z + bb, acc1.w + bb);
        if (co1 >= 18) {
            r.x = 1.f / (1.f + expf(-r.x));
            r.y = 1.f / (1.f + expf(-r.y));
            r.z = 1.f / (1.f + expf(-r.z));
            r.w = 1.f / (1.f + expf(-r.w));
        }
        *(float4*)(om + (((size_t)(b * OC + co1)) << 12) + (h << 6) + wpx) = r;
    }
}

// ---------------- K2: bilinear sampling (NHWC bf16) + MFMA GEMM ----------------
__global__ __launch_bounds__(256) void k_sample_gemm(const u16* __restrict__ xtb,
                                                     const float* __restrict__ om,
                                                     const u16* __restrict__ wbf,
                                                     const float* __restrict__ bias,
                                                     float* __restrict__ out) {
    __shared__ __align__(16) u16 Abuf[2][4096];      // [buf][32px][128ch] bf16, swizzled
    __shared__ int   y0c[288], y1c[288], x0c[288], x1c[288];
    __shared__ float w4[288][4];

    const int t   = threadIdx.x;
    const int pp0 = blockIdx.x << 5;
    const int b   = blockIdx.x >> 7;
    const int h   = (pp0 >> 6) & 63;
    const int w0  = pp0 & 63;

    for (int i = t; i < 288; i += 256) {
        int p  = i / 9;
        int tt = i - p * 9;
        int w  = w0 + p;
        const float* ob = om + ((size_t)b * OC) * 4096 + (h << 6) + w;
        float dy = ob[(size_t)tt << 12];
        float dx = ob[(size_t)(9 + tt) << 12];
        float m  = ob[(size_t)(18 + tt) << 12];   // sigmoided in K1
        float py = dy + (float)(h - 1 + tt / 3);
        float px = dx + (float)(w - 1 + tt % 3);
        float y0f = floorf(py), x0f = floorf(px);
        float wy = py - y0f, wx = px - x0f;
        int y0 = (int)y0f, x0 = (int)x0f;
        int y1 = y0 + 1,   x1 = x0 + 1;
        float vy0 = ((unsigned)y0 < 64u) ? 1.f : 0.f;
        float vy1 = ((unsigned)y1 < 64u) ? 1.f : 0.f;
        float vx0 = ((unsigned)x0 < 64u) ? 1.f : 0.f;
        float vx1 = ((unsigned)x1 < 64u) ? 1.f : 0.f;
        w4[i][0] = (1.f - wy) * (1.f - wx) * m * vy0 * vx0;
        w4[i][1] = (1.f - wy) * wx         * m * vy0 * vx1;
        w4[i][2] = wy         * (1.f - wx) * m * vy1 * vx0;
        w4[i][3] = wy         * wx         * m * vy1 * vx1;
        y0c[i] = min(max(y0, 0), 63);
        y1c[i] = min(max(y1, 0), 63);
        x0c[i] = min(max(x0, 0), 63);
        x1c[i] = min(max(x1, 0), 63);
    }
    __syncthreads();

    f32x4 acc00 = {0.f, 0.f, 0.f, 0.f};
    f32x4 acc01 = {0.f, 0.f, 0.f, 0.f};
    f32x4 acc10 = {0.f, 0.f, 0.f, 0.f};
    f32x4 acc11 = {0.f, 0.f, 0.f, 0.f};

    const int p  = t >> 3;
    const int cg = t & 7;
    const u16* xb = xtb + ((size_t)b << 19);

    const int l   = t & 63;
    const int wv  = t >> 6;
    const int row0 = l & 15;
    const int kg   = l >> 4;

    auto sample = [&](int tt, int buf) {
        int pi = p * 9 + tt;
        int o00 = ((y0c[pi] << 6) | x0c[pi]) << 7;
        int o01 = ((y0c[pi] << 6) | x1c[pi]) << 7;
        int o10 = ((y1c[pi] << 6) | x0c[pi]) << 7;
        int o11 = ((y1c[pi] << 6) | x1c[pi]) << 7;
        float W00 = w4[pi][0], W01 = w4[pi][1], W10 = w4[pi][2], W11 = w4[pi][3];
        u16* dst = &Abuf[buf][0];
#pragma unroll
        for (int it = 0; it < 4; ++it) {
            int ch = it * 32 + cg * 4;
            ushort4 v00 = *(const ushort4*)(xb + o00 + ch);
            ushort4 v01 = *(const ushort4*)(xb + o01 + ch);
            ushort4 v10 = *(const ushort4*)(xb + o10 + ch);
            ushort4 v11 = *(const ushort4*)(xb + o11 + ch);
            float r0 = W00 * b2f(v00.x) + W01 * b2f(v01.x) + W10 * b2f(v10.x) + W11 * b2f(v11.x);
            float r1 = W00 * b2f(v00.y) + W01 * b2f(v01.y) + W10 * b2f(v10.y) + W11 * b2f(v11.y);
            float r2 = W00 * b2f(v00.z) + W01 * b2f(v01.z) + W10 * b2f(v10.z) + W11 * b2f(v11.z);
            float r3 = W00 * b2f(v00.w) + W01 * b2f(v01.w) + W10 * b2f(v10.w) + W11 * b2f(v11.w);
            ushort4 rv;
            rv.x = f2b(r0); rv.y = f2b(r1); rv.z = f2b(r2); rv.w = f2b(r3);
            int q = ch >> 3;
            int byteoff = (p << 8) + (((q ^ (p & 15)) << 4)) + ((cg & 1) << 3);
            *(ushort4*)((char*)dst + byteoff) = rv;
        }
    };

    auto domfma = [&](int t9, int buf) {
        const char* Ab = (const char*)&Abuf[buf][0];
#pragma unroll
        for (int s = 0; s < 4; ++s) {
            int q = s * 4 + kg;
            int sw = (q ^ row0) << 4;
            bf16x8 a0 = *(const bf16x8*)(Ab + (row0 << 8) + sw);
            bf16x8 a1 = *(const bf16x8*)(Ab + ((row0 + 16) << 8) + ((q ^ row0) << 4));
            size_t wo = ((size_t)t9 << 14) + (s << 12) + ((size_t)(wv * 2) << 9) + (l << 3);
            bf16x8 b0 = *(const bf16x8*)(wbf + wo);
            bf16x8 b1 = *(const bf16x8*)(wbf + wo + 512);
            acc00 = __builtin_amdgcn_mfma_f32_16x16x32_bf16(a0, b0, acc00, 0, 0, 0);
            acc10 = __builtin_amdgcn_mfma_f32_16x16x32_bf16(a1, b0, acc10, 0, 0, 0);
            acc01 = __builtin_amdgcn_mfma_f32_16x16x32_bf16(a0, b1, acc01, 0, 0, 0);
            acc11 = __builtin_amdgcn_mfma_f32_16x16x32_bf16(a1, b1, acc11, 0, 0, 0);
        }
    };

    sample(0, 0);
    __syncthreads();
    for (int tt = 0; tt < 9; ++tt) {
        if (tt < 8) sample(tt + 1, (tt + 1) & 1);
        domfma(tt, tt & 1);
        __syncthreads();
    }

    {
        float* outs = (float*)&Abuf[0][0];
        int colbase = wv * 32 + row0;
        int pxg = kg << 2;
        auto st = [&](int co, int px, f32x4 v) {
            *(f32x4*)((char*)outs + (co << 7) + ((((px >> 2) ^ (co & 7))) << 4)) = v;
        };
        st(colbase,      pxg,      acc00);
        st(colbase,      pxg + 16, acc10);
        st(colbase + 16, pxg,      acc01);
        st(colbase + 16, pxg + 16, acc11);
    }
    __syncthreads();
    {
        const float* outs = (const float*)&Abuf[0][0];
        int co = t >> 1, half = t & 1;
        float bb = bias[co];
        float* og = out + (((size_t)(b * COUT + co)) << 12) + (h << 6) + w0 + half * 16;
#pragma unroll
        for (int j = 0; j < 4; ++j) {
            int px = half * 16 + j * 4;
            f32x4 v = *(const f32x4*)((const char*)outs + (co << 7) + ((((px >> 2) ^ (co & 7))) << 4));
            float4 r = make_float4(v.x + bb, v.y + bb, v.z + bb, v.w + bb);
            *reinterpret_cast<float4*>(og + j * 4) = r;
        }
    }
}

// ---------------- host ----------------
extern "C" void kernel_launch(void* const* d_in, const int* in_sizes, int n_in,
                              void* d_out, int out_size, void* d_ws, size_t ws_size,
                              hipStream_t stream) {
    const float* x      = (const float*)d_in[0];
    const float* w_off  = (const float*)d_in[1];
    const float* b_off  = (const float*)d_in[2];
    const float* weight = (const float*)d_in[3];
    const float* bias   = (const float*)d_in[4];
    float* out = (float*)d_out;

    float* om  = (float*)d_ws;                        // 884736 f32
    u16*   xtb = (u16*)(om + 884736);                 // 4194304 u16 (NHWC bf16 hi)
    u16*   wbf = xtb + 4194304;                       // 147456 u16 (main B-frags)
    u16*   wop = wbf + 147456;                        // 73728 u16 (offset B-frags hi/lo)
    u16*   xlo = (u16*)d_out;                         // 8 MB scratch inside out (16.7 MB);
                                                      // consumed before k_sample_gemm writes out

    k_transpose_x<<<1024, 256, 0, stream>>>(x, xtb, xlo);
    k_pack_w<<<576, 256, 0, stream>>>(weight, wbf);
    k_pack_woff<<<288, 256, 0, stream>>>(w_off, wop);
    k_off_mfma<<<1024, 128, 0, stream>>>(xtb, xlo, wop, b_off, om);
    k_sample_gemm<<<BATCH * HH * WW / 32, 256, 0, stream>>>(xtb, om, wbf, bias, out);
}